// Round 1
// baseline (371.965 us; speedup 1.0000x reference)
//
#include <hip/hip_runtime.h>

static constexpr int S    = 2048;
static constexpr int D    = 64;
static constexpr int TQ   = 64;   // q rows per block
static constexpr int TK   = 64;   // k cols per tile
static constexpr int LSTR = 68;   // padded LDS row stride (floats): 2-way read conflicts only

__global__ __launch_bounds__(256, 4)
void monotonic_attn_probs(const float* __restrict__ Q,
                          const float* __restrict__ K,
                          float* __restrict__ out)
{
    const int b  = blockIdx.y;
    const int qt = (int)gridDim.x - 1 - (int)blockIdx.x;  // big tiles dispatch first
    const int q0 = qt * TQ;
    const int kend = q0 + TQ;     // exclusive bound of k needing compute (causal)

    const int tid = threadIdx.x;
    const int tx  = tid & 15;     // 16 col-groups
    const int ty  = tid >> 4;     // 16 row-groups

    __shared__ float Qs[TQ][LSTR];
    __shared__ float Ks[TK][LSTR];

    const float* __restrict__ Qb = Q + (size_t)b * S * D;
    const float* __restrict__ Kb = K + (size_t)b * S * D;
    float* __restrict__ outb = out + (size_t)b * (size_t)S * S;

    // ---- stage Q tile (rows q0..q0+63), coalesced float4 ----
    {
        const int d0 = tx * 4;
        int r = ty;
        #pragma unroll
        for (int it = 0; it < 4; ++it, r += 16) {
            const float4 v = *reinterpret_cast<const float4*>(&Qb[(q0 + r) * D + d0]);
            *reinterpret_cast<float4*>(&Qs[r][d0]) = v;
        }
    }

    const int rg0 = q0 + 4 * ty;  // this thread's first global row
    const int cl0 = 4 * tx;       // this thread's first col within the tile

    auto stage_k = [&](int k0) {
        const int d0 = tx * 4;
        int r = ty;
        #pragma unroll
        for (int it = 0; it < 4; ++it, r += 16) {
            const float4 v = *reinterpret_cast<const float4*>(&Kb[(k0 + r) * D + d0]);
            *reinterpret_cast<float4*>(&Ks[r][d0]) = v;
        }
    };

    auto compute = [&](float (&acc)[4][4]) {
        #pragma unroll
        for (int i = 0; i < 4; ++i)
            #pragma unroll
            for (int j = 0; j < 4; ++j)
                acc[i][j] = 0.0f;
        for (int d = 0; d < D; d += 4) {
            float4 qv[4], kv[4];
            #pragma unroll
            for (int i = 0; i < 4; ++i)
                qv[i] = *reinterpret_cast<const float4*>(&Qs[4 * ty + i][d]);
            #pragma unroll
            for (int j = 0; j < 4; ++j)
                kv[j] = *reinterpret_cast<const float4*>(&Ks[4 * tx + j][d]);
            #pragma unroll
            for (int i = 0; i < 4; ++i)
                #pragma unroll
                for (int j = 0; j < 4; ++j)
                    acc[i][j] += qv[i].x * kv[j].x + qv[i].y * kv[j].y
                               + qv[i].z * kv[j].z + qv[i].w * kv[j].w;
        }
    };

    // ---- pass A: per-row sum of exp(s) (no max-subtraction needed: |s| <~ 7) ----
    float rsum[4] = {0.f, 0.f, 0.f, 0.f};
    for (int k0 = 0; k0 < kend; k0 += TK) {
        __syncthreads();
        stage_k(k0);
        __syncthreads();
        float acc[4][4];
        compute(acc);
        #pragma unroll
        for (int i = 0; i < 4; ++i) {
            const int rg = rg0 + i;
            #pragma unroll
            for (int j = 0; j < 4; ++j) {
                const int cg = k0 + cl0 + j;
                if (cg <= rg) rsum[i] += __expf(acc[i][j] * 0.125f);
            }
        }
    }

    // butterfly-reduce across the 16 lanes sharing each row (lanes differ in low 4 bits)
    #pragma unroll
    for (int i = 0; i < 4; ++i) {
        float v = rsum[i];
        v += __shfl_xor(v, 1);
        v += __shfl_xor(v, 2);
        v += __shfl_xor(v, 4);
        v += __shfl_xor(v, 8);
        rsum[i] = v;
    }
    float inv[4];
    #pragma unroll
    for (int i = 0; i < 4; ++i) inv[i] = 1.0f / rsum[i];

    // ---- pass B: recompute scores, write normalized probs ----
    for (int k0 = 0; k0 < kend; k0 += TK) {
        __syncthreads();
        stage_k(k0);
        __syncthreads();
        float acc[4][4];
        compute(acc);
        #pragma unroll
        for (int i = 0; i < 4; ++i) {
            const int rg = rg0 + i;
            float vals[4];
            #pragma unroll
            for (int j = 0; j < 4; ++j) {
                const int cg = k0 + cl0 + j;
                vals[j] = (cg <= rg) ? __expf(acc[i][j] * 0.125f) * inv[i] : 0.0f;
            }
            float4 o;
            o.x = vals[0]; o.y = vals[1]; o.z = vals[2]; o.w = vals[3];
            *reinterpret_cast<float4*>(&outb[(size_t)rg * S + k0 + cl0]) = o;
        }
    }

    // ---- zero-fill the strictly-masked region (cols kend..S) ----
    for (int r = ty; r < TQ; r += 16) {
        const size_t rowbase = (size_t)(q0 + r) * S;
        for (int c = kend + tx * 4; c < S; c += 64) {
            *reinterpret_cast<float4*>(&outb[rowbase + c]) = float4{0.f, 0.f, 0.f, 0.f};
        }
    }
}

extern "C" void kernel_launch(void* const* d_in, const int* in_sizes, int n_in,
                              void* d_out, int out_size, void* d_ws, size_t ws_size,
                              hipStream_t stream)
{
    const float* Q = (const float*)d_in[0];
    const float* K = (const float*)d_in[1];
    float* out     = (float*)d_out;
    const int B    = in_sizes[0] / (S * D);

    dim3 grid(S / TQ, B);
    monotonic_attn_probs<<<grid, 256, 0, stream>>>(Q, K, out);
}

// Round 2
// 121.736 us; speedup vs baseline: 3.0555x; 3.0555x over previous
//
#include <hip/hip_runtime.h>

using bf16x8 = __attribute__((ext_vector_type(8))) short;
using u16x8  = __attribute__((ext_vector_type(8))) unsigned short;
using f32x4  = __attribute__((ext_vector_type(4))) float;

static constexpr int S  = 2048;
static constexpr int D  = 64;
static constexpr int TQ = 64;
static constexpr int TK = 64;
static constexpr float QSCALE = 0.18033688f; // log2(e)/8 : exp2(dot) == exp(dot/8)

__device__ __forceinline__ unsigned short bf16_rne(float x) {
    unsigned u = __builtin_bit_cast(unsigned, x);
    u += 0x7FFFu + ((u >> 16) & 1u);
    return (unsigned short)(u >> 16);
}
__device__ __forceinline__ float bf16_f32(unsigned short h) {
    unsigned u = ((unsigned)h) << 16;
    return __builtin_bit_cast(float, u);
}
__device__ __forceinline__ f32x4 mfma16(bf16x8 a, bf16x8 b, f32x4 c) {
    return __builtin_amdgcn_mfma_f32_16x16x32_bf16(a, b, c, 0, 0, 0);
}

// Block: one 64-row q-strip of one batch. 4 waves; wave w owns k-subtile w (16 cols)
// of each 64-col K tile and ALL 64 q rows (Q hi/lo fragments in registers).
// MFMA operands swapped (A=K, B=Q) so each lane's 4 acc values are 4 consecutive k
// of one q row -> dwordx4 stores.
__global__ __launch_bounds__(256, 2)
void monotonic_attn_mfma(const float* __restrict__ Qg,
                         const float* __restrict__ Kg,
                         float* __restrict__ out)
{
    __shared__ unsigned short lds[8192];   // Q stage: hi [0,4096) lo [4096,8192); K stage: hi [0,4096)
    __shared__ float red[4][64];

    // chunked XCD swizzle (bijective: gridDim.x % 8 == 0): 64 consecutive work-ids per XCD
    const int h   = blockIdx.x;
    const int wid = (h & 7) * ((int)gridDim.x >> 3) + (h >> 3);
    const int b   = wid >> 5;              // 32 strips per batch
    const int qt  = 31 - (wid & 31);       // big strips first (LPT within XCD)
    const int q0  = qt * TQ;
    const int nt  = qt + 1;                // K tiles needed (causal)
    const int kend = q0 + TQ;

    const int tid  = threadIdx.x;
    const int lane = tid & 63;
    const int wv   = tid >> 6;             // wave id = k-subtile owner
    const int l15  = lane & 15;
    const int g    = lane >> 4;

    const float* __restrict__ Qb = Qg + (size_t)b * S * D;
    const float* __restrict__ Kb = Kg + (size_t)b * S * D;
    float* __restrict__ outb = out + (size_t)b * (size_t)S * S;

    const int srow = tid >> 2;             // staging: row 0..63
    const int scp  = tid & 3;              // 16-float chunk pair within row

    // ---------------- stage Q (scaled, hi+lo planes, XOR-swizzled) ----------------
    {
        const float4* src = reinterpret_cast<const float4*>(Qb + (q0 + srow) * D + 16 * scp);
        float4 f0 = src[0], f1 = src[1], f2 = src[2], f3 = src[3];
        float v[16];
        *reinterpret_cast<float4*>(&v[0])  = f0;
        *reinterpret_cast<float4*>(&v[4])  = f1;
        *reinterpret_cast<float4*>(&v[8])  = f2;
        *reinterpret_cast<float4*>(&v[12]) = f3;
        #pragma unroll
        for (int c2 = 0; c2 < 2; ++c2) {
            u16x8 hv, lv;
            #pragma unroll
            for (int i = 0; i < 8; ++i) {
                float s = v[c2 * 8 + i] * QSCALE;
                unsigned short hb = bf16_rne(s);
                hv[i] = hb;
                lv[i] = bf16_rne(s - bf16_f32(hb));
            }
            const int off = srow * 64 + ((((scp << 1) | c2)) ^ (srow & 7)) * 8;
            *reinterpret_cast<u16x8*>(&lds[off])        = hv;
            *reinterpret_cast<u16x8*>(&lds[4096 + off]) = lv;
        }
    }
    __syncthreads();

    // ---------------- Q fragments -> registers (all 4 q-subtiles, hi+lo) ----------------
    bf16x8 qhi[4][2], qlo[4][2];
    #pragma unroll
    for (int qs = 0; qs < 4; ++qs) {
        const int row = qs * 16 + l15;
        #pragma unroll
        for (int c = 0; c < 2; ++c) {
            const int off = row * 64 + ((((c << 2) | g)) ^ (row & 7)) * 8;
            qhi[qs][c] = *reinterpret_cast<const bf16x8*>(&lds[off]);
            qlo[qs][c] = *reinterpret_cast<const bf16x8*>(&lds[4096 + off]);
        }
    }

    // K fragment LDS offsets (constant across tiles)
    const int krow  = wv * 16 + l15;
    const int koff0 = krow * 64 + ((g)      ^ (krow & 7)) * 8;  // chunk idx (0<<2)|g
    const int koff1 = krow * 64 + ((4 | g)  ^ (krow & 7)) * 8;  // chunk idx (1<<2)|g

    float4 pfa, pfb, pfc, pfd;   // register prefetch of next K tile (T14)
    auto issue_pf = [&](int k0) {
        const float4* src = reinterpret_cast<const float4*>(Kb + (k0 + srow) * D + 16 * scp);
        pfa = src[0]; pfb = src[1]; pfc = src[2]; pfd = src[3];
    };
    auto write_stage = [&]() {
        float v[16];
        *reinterpret_cast<float4*>(&v[0])  = pfa;
        *reinterpret_cast<float4*>(&v[4])  = pfb;
        *reinterpret_cast<float4*>(&v[8])  = pfc;
        *reinterpret_cast<float4*>(&v[12]) = pfd;
        #pragma unroll
        for (int c2 = 0; c2 < 2; ++c2) {
            u16x8 hv;
            #pragma unroll
            for (int i = 0; i < 8; ++i) hv[i] = bf16_rne(v[c2 * 8 + i]);
            const int off = srow * 64 + ((((scp << 1) | c2)) ^ (srow & 7)) * 8;
            *reinterpret_cast<u16x8*>(&lds[off]) = hv;
        }
    };

    // ---------------- pass A: per-row sums of exp ----------------
    float rsum[4] = {0.f, 0.f, 0.f, 0.f};
    issue_pf(0);
    for (int t = 0; t < nt; ++t) {
        const int k0 = t * TK;
        __syncthreads();
        write_stage();
        __syncthreads();
        if (t + 1 < nt) issue_pf(k0 + TK);
        const bf16x8 kf0 = *reinterpret_cast<const bf16x8*>(&lds[koff0]);
        const bf16x8 kf1 = *reinterpret_cast<const bf16x8*>(&lds[koff1]);
        const int klo = k0 + wv * 16;
        const int kb  = klo + g * 4;
        #pragma unroll
        for (int qs = 0; qs < 4; ++qs) {
            const int qmin = q0 + qs * 16;
            if (klo > qmin + 15) continue;               // fully masked (diag tile only)
            f32x4 acc = {0.f, 0.f, 0.f, 0.f};
            acc = mfma16(kf0, qhi[qs][0], acc);
            acc = mfma16(kf1, qhi[qs][1], acc);
            acc = mfma16(kf0, qlo[qs][0], acc);
            acc = mfma16(kf1, qlo[qs][1], acc);
            const int qg = qmin + l15;
            if (klo + 15 <= qmin) {                      // fully unmasked
                rsum[qs] += exp2f(acc[0]) + exp2f(acc[1]) + exp2f(acc[2]) + exp2f(acc[3]);
            } else {
                #pragma unroll
                for (int r = 0; r < 4; ++r)
                    rsum[qs] += (kb + r <= qg) ? exp2f(acc[r]) : 0.f;
            }
        }
    }
    #pragma unroll
    for (int qs = 0; qs < 4; ++qs) {
        float v = rsum[qs];
        v += __shfl_xor(v, 16);
        v += __shfl_xor(v, 32);
        rsum[qs] = v;
    }
    if (g == 0) {
        #pragma unroll
        for (int qs = 0; qs < 4; ++qs) red[wv][qs * 16 + l15] = rsum[qs];
    }
    __syncthreads();
    float inv[4];
    #pragma unroll
    for (int qs = 0; qs < 4; ++qs) {
        const int qi = qs * 16 + l15;
        inv[qs] = 1.f / (red[0][qi] + red[1][qi] + red[2][qi] + red[3][qi]);
    }

    // ---------------- pass B: recompute, normalize, write ----------------
    issue_pf(0);
    for (int t = 0; t < nt; ++t) {
        const int k0 = t * TK;
        __syncthreads();
        write_stage();
        __syncthreads();
        if (t + 1 < nt) issue_pf(k0 + TK);
        const bf16x8 kf0 = *reinterpret_cast<const bf16x8*>(&lds[koff0]);
        const bf16x8 kf1 = *reinterpret_cast<const bf16x8*>(&lds[koff1]);
        const int klo = k0 + wv * 16;
        const int kb  = klo + g * 4;
        #pragma unroll
        for (int qs = 0; qs < 4; ++qs) {
            const int qmin = q0 + qs * 16;
            const int qg   = qmin + l15;
            float4 ov; ov.x = 0.f; ov.y = 0.f; ov.z = 0.f; ov.w = 0.f;
            if (klo <= qmin + 15) {
                f32x4 acc = {0.f, 0.f, 0.f, 0.f};
                acc = mfma16(kf0, qhi[qs][0], acc);
                acc = mfma16(kf1, qhi[qs][1], acc);
                acc = mfma16(kf0, qlo[qs][0], acc);
                acc = mfma16(kf1, qlo[qs][1], acc);
                if (klo + 15 <= qmin) {
                    ov.x = exp2f(acc[0]) * inv[qs];
                    ov.y = exp2f(acc[1]) * inv[qs];
                    ov.z = exp2f(acc[2]) * inv[qs];
                    ov.w = exp2f(acc[3]) * inv[qs];
                } else {
                    ov.x = (kb + 0 <= qg) ? exp2f(acc[0]) * inv[qs] : 0.f;
                    ov.y = (kb + 1 <= qg) ? exp2f(acc[1]) * inv[qs] : 0.f;
                    ov.z = (kb + 2 <= qg) ? exp2f(acc[2]) * inv[qs] : 0.f;
                    ov.w = (kb + 3 <= qg) ? exp2f(acc[3]) * inv[qs] : 0.f;
                }
            }
            *reinterpret_cast<float4*>(&outb[(size_t)qg * S + kb]) = ov;
        }
    }

    // ---------------- zero-fill columns >= kend ----------------
    {
        float4 z; z.x = 0.f; z.y = 0.f; z.z = 0.f; z.w = 0.f;
        const size_t rb = (size_t)(q0 + srow) * S;
        for (int c = kend + scp * 4; c < S; c += 16)
            *reinterpret_cast<float4*>(&outb[rb + c]) = z;
    }
}

extern "C" void kernel_launch(void* const* d_in, const int* in_sizes, int n_in,
                              void* d_out, int out_size, void* d_ws, size_t ws_size,
                              hipStream_t stream)
{
    const float* Q = (const float*)d_in[0];
    const float* K = (const float*)d_in[1];
    float* out     = (float*)d_out;
    const int nb   = in_sizes[0] / (S * D);

    monotonic_attn_mfma<<<dim3(nb * (S / TQ)), dim3(256), 0, stream>>>(Q, K, out);
}

// Round 3
// 94.356 us; speedup vs baseline: 3.9422x; 1.2902x over previous
//
#include <hip/hip_runtime.h>

using bf16x8 = __attribute__((ext_vector_type(8))) short;
using u16x8  = __attribute__((ext_vector_type(8))) unsigned short;
using f32x4  = __attribute__((ext_vector_type(4))) float;

static constexpr int S  = 2048;
static constexpr int D  = 64;
static constexpr int TQ = 64;
static constexpr int TK = 128;
static constexpr float QSCALE = 0.18033688f; // log2(e)/8 : exp2(dot) == exp(dot/8)

__device__ __forceinline__ unsigned short bf16_rne(float x) {
    unsigned u = __builtin_bit_cast(unsigned, x);
    u += 0x7FFFu + ((u >> 16) & 1u);
    return (unsigned short)(u >> 16);
}
__device__ __forceinline__ float bf16_f32(unsigned short h) {
    unsigned u = ((unsigned)h) << 16;
    return __builtin_bit_cast(float, u);
}
__device__ __forceinline__ f32x4 mfma16(bf16x8 a, bf16x8 b, f32x4 c) {
    return __builtin_amdgcn_mfma_f32_16x16x32_bf16(a, b, c, 0, 0, 0);
}

// One block = one batch + one COMPLEMENTARY strip pair (qt, 31-qt): exactly 33
// K-tiles per pass per block -> perfect static load balance. 8 waves; wave wv
// owns 16 k-cols of each 128-col K tile and all 64 q rows (Q hi/lo in regs).
// MFMA swapped (A=K, B=Q): lane's 4 acc values = 4 consecutive k of one q row.
__global__ __launch_bounds__(512, 1)
void monotonic_attn_mfma(const float* __restrict__ Qg,
                         const float* __restrict__ Kg,
                         float* __restrict__ out)
{
    __shared__ unsigned short lds[8192];   // 16 KB: Q stage hi[0,4096) lo[4096,8192); K stage [0,8192)
    __shared__ float red[8][64];

    // XCD-chunk swizzle (grid % 8 == 0): XCD c hosts wids [c*grid/8, ...) -> 2 batches/XCD
    const int bid  = blockIdx.x;
    const int wid  = (bid & 7) * ((int)gridDim.x >> 3) + (bid >> 3);
    const int b    = wid >> 4;
    const int pair = wid & 15;

    const int tid  = threadIdx.x;
    const int lane = tid & 63;
    const int wv   = tid >> 6;             // 0..7 : k-subtile owner
    const int l15  = lane & 15;
    const int g    = lane >> 4;

    const float* __restrict__ Qb = Qg + (size_t)b * S * D;
    const float* __restrict__ Kb = Kg + (size_t)b * S * D;
    float* __restrict__ outb = out + (size_t)b * (size_t)S * S;

    const int srow = tid >> 2;             // K staging: row 0..127
    const int scp  = tid & 3;              // 16-float chunk pair
    const int qrow = tid >> 3;             // Q staging: row 0..63
    const int qcp  = tid & 7;              // 8-float chunk

    // K fragment LDS offsets (constant across tiles)
    const int krow  = wv * 16 + l15;
    const int koff0 = krow * 64 + ((g)     ^ (krow & 7)) * 8;
    const int koff1 = krow * 64 + ((4 | g) ^ (krow & 7)) * 8;

    float4 pfa, pfb, pfc, pfd;             // register prefetch of next K tile

    for (int half = 0; half < 2; ++half) {
        const int qt = half ? pair : (31 - pair);
        const int q0 = qt * TQ;
        const int nt = (qt + 2) >> 1;      // ceil((q0+64)/128) K tiles

        // ---------------- stage Q (scaled, hi+lo planes, XOR-swizzled) ----------------
        __syncthreads();                   // previous strip's K reads done
        {
            const float4* src = reinterpret_cast<const float4*>(Qb + (size_t)(q0 + qrow) * D + qcp * 8);
            const float4 f0 = src[0], f1 = src[1];
            float v[8];
            *reinterpret_cast<float4*>(&v[0]) = f0;
            *reinterpret_cast<float4*>(&v[4]) = f1;
            u16x8 hv, lv;
            #pragma unroll
            for (int i = 0; i < 8; ++i) {
                const float s = v[i] * QSCALE;
                const unsigned short hb = bf16_rne(s);
                hv[i] = hb;
                lv[i] = bf16_rne(s - bf16_f32(hb));
            }
            const int off = qrow * 64 + (qcp ^ (qrow & 7)) * 8;
            *reinterpret_cast<u16x8*>(&lds[off])        = hv;
            *reinterpret_cast<u16x8*>(&lds[4096 + off]) = lv;
        }
        __syncthreads();

        // ---------------- Q fragments -> registers ----------------
        bf16x8 qhi[4][2], qlo[4][2];
        #pragma unroll
        for (int qs = 0; qs < 4; ++qs) {
            const int row = qs * 16 + l15;
            #pragma unroll
            for (int c = 0; c < 2; ++c) {
                const int off = row * 64 + (((c << 2) | g) ^ (row & 7)) * 8;
                qhi[qs][c] = *reinterpret_cast<const bf16x8*>(&lds[off]);
                qlo[qs][c] = *reinterpret_cast<const bf16x8*>(&lds[4096 + off]);
            }
        }
        __syncthreads();                   // Q reads done before K staging overwrites

        float inv4[4];
        for (int pass = 0; pass < 2; ++pass) {
            float rsum[4] = {0.f, 0.f, 0.f, 0.f};
            {   // prefetch tile 0
                const float4* src = reinterpret_cast<const float4*>(Kb + (size_t)srow * D + scp * 16);
                pfa = src[0]; pfb = src[1]; pfc = src[2]; pfd = src[3];
            }
            for (int t = 0; t < nt; ++t) {
                const int k0 = t * TK;
                __syncthreads();
                {   // write staged K tile (bf16, XOR-swizzled)
                    float v[16];
                    *reinterpret_cast<float4*>(&v[0])  = pfa;
                    *reinterpret_cast<float4*>(&v[4])  = pfb;
                    *reinterpret_cast<float4*>(&v[8])  = pfc;
                    *reinterpret_cast<float4*>(&v[12]) = pfd;
                    #pragma unroll
                    for (int c2 = 0; c2 < 2; ++c2) {
                        u16x8 hv;
                        #pragma unroll
                        for (int i = 0; i < 8; ++i) hv[i] = bf16_rne(v[c2 * 8 + i]);
                        const int off = srow * 64 + (((scp << 1) | c2) ^ (srow & 7)) * 8;
                        *reinterpret_cast<u16x8*>(&lds[off]) = hv;
                    }
                }
                __syncthreads();
                if (t + 1 < nt) {          // prefetch next tile under compute
                    const float4* src = reinterpret_cast<const float4*>(Kb + (size_t)(k0 + TK + srow) * D + scp * 16);
                    pfa = src[0]; pfb = src[1]; pfc = src[2]; pfd = src[3];
                }
                const bf16x8 kf0 = *reinterpret_cast<const bf16x8*>(&lds[koff0]);
                const bf16x8 kf1 = *reinterpret_cast<const bf16x8*>(&lds[koff1]);
                const int klo = k0 + wv * 16;
                const int kb  = klo + g * 4;
                #pragma unroll
                for (int qs = 0; qs < 4; ++qs) {
                    const int qmin = q0 + qs * 16;
                    const int qg   = qmin + l15;
                    if (pass == 0) {
                        if (klo > qmin + 15) continue;       // fully masked k-sub
                        f32x4 acc = {0.f, 0.f, 0.f, 0.f};
                        acc = mfma16(kf0, qhi[qs][0], acc);
                        acc = mfma16(kf1, qhi[qs][1], acc);
                        acc = mfma16(kf0, qlo[qs][0], acc);
                        acc = mfma16(kf1, qlo[qs][1], acc);
                        if (klo + 15 <= qmin) {
                            rsum[qs] += exp2f(acc[0]) + exp2f(acc[1]) + exp2f(acc[2]) + exp2f(acc[3]);
                        } else {
                            #pragma unroll
                            for (int r = 0; r < 4; ++r)
                                rsum[qs] += (kb + r <= qg) ? exp2f(acc[r]) : 0.f;
                        }
                    } else {
                        float4 ov; ov.x = 0.f; ov.y = 0.f; ov.z = 0.f; ov.w = 0.f;
                        if (klo <= qmin + 15) {
                            f32x4 acc = {0.f, 0.f, 0.f, 0.f};
                            acc = mfma16(kf0, qhi[qs][0], acc);
                            acc = mfma16(kf1, qhi[qs][1], acc);
                            acc = mfma16(kf0, qlo[qs][0], acc);
                            acc = mfma16(kf1, qlo[qs][1], acc);
                            if (klo + 15 <= qmin) {
                                ov.x = exp2f(acc[0]) * inv4[qs];
                                ov.y = exp2f(acc[1]) * inv4[qs];
                                ov.z = exp2f(acc[2]) * inv4[qs];
                                ov.w = exp2f(acc[3]) * inv4[qs];
                            } else {
                                ov.x = (kb + 0 <= qg) ? exp2f(acc[0]) * inv4[qs] : 0.f;
                                ov.y = (kb + 1 <= qg) ? exp2f(acc[1]) * inv4[qs] : 0.f;
                                ov.z = (kb + 2 <= qg) ? exp2f(acc[2]) * inv4[qs] : 0.f;
                                ov.w = (kb + 3 <= qg) ? exp2f(acc[3]) * inv4[qs] : 0.f;
                            }
                        }
                        *reinterpret_cast<float4*>(&outb[(size_t)qg * S + kb]) = ov;
                    }
                }
            }
            if (pass == 0) {               // cross-wave row-sum reduction
                #pragma unroll
                for (int qs = 0; qs < 4; ++qs) {
                    float v = rsum[qs];
                    v += __shfl_xor(v, 16);
                    v += __shfl_xor(v, 32);
                    if (g == 0) red[wv][qs * 16 + l15] = v;
                }
                __syncthreads();
                #pragma unroll
                for (int qs = 0; qs < 4; ++qs) {
                    const int qi = qs * 16 + l15;
                    inv4[qs] = 1.f / (red[0][qi] + red[1][qi] + red[2][qi] + red[3][qi]
                                    + red[4][qi] + red[5][qi] + red[6][qi] + red[7][qi]);
                }
            }
        }

        // ---------------- zero-fill columns >= nt*TK ----------------
        {
            const int c0 = nt * TK;
            float4 z; z.x = 0.f; z.y = 0.f; z.z = 0.f; z.w = 0.f;
            const size_t rb = (size_t)(q0 + (tid >> 3)) * S;
            for (int cc = c0 + (tid & 7) * 4; cc < S; cc += 32)
                *reinterpret_cast<float4*>(&outb[rb + cc]) = z;
        }
    }
}

extern "C" void kernel_launch(void* const* d_in, const int* in_sizes, int n_in,
                              void* d_out, int out_size, void* d_ws, size_t ws_size,
                              hipStream_t stream)
{
    const float* Q = (const float*)d_in[0];
    const float* K = (const float*)d_in[1];
    float* out     = (float*)d_out;
    const int nb   = in_sizes[0] / (S * D);   // batches (16)

    monotonic_attn_mfma<<<dim3(nb * 16), dim3(512), 0, stream>>>(Q, K, out);
}